// Round 1
// baseline (838.300 us; speedup 1.0000x reference)
//
#include <hip/hip_runtime.h>

// Input x: (8, 64, 512, 512) fp32 = 512 planes of 512x512.
// Output: ll|lh|hl|hh concatenated, each (8, 64, 256, 256) fp32.
//
// Each thread computes 2 adjacent output pixels (i, 2*j2), (i, 2*j2+1):
//   reads float4 from input row 2i   -> a0 b0 a1 b1
//   reads float4 from input row 2i+1 -> c0 d0 c1 d1
//   writes float2 to each of the 4 subband planes.

constexpr int kPlanes   = 8 * 64;          // 512
constexpr int kW        = 512;
constexpr int kOutHW    = 256;
constexpr long long kOutPlane  = (long long)kOutHW * kOutHW;        // 65536
constexpr long long kOutRegion = (long long)kPlanes * kOutPlane;    // 33554432

__global__ __launch_bounds__(256) void dwt2d_haar_kernel(
    const float* __restrict__ x, float* __restrict__ out) {
    int tid = blockIdx.x * blockDim.x + threadIdx.x;
    // tid layout: p [0,512) : i [0,256) : j2 [0,128)
    int p   = tid >> 15;
    int rem = tid & 32767;
    int i   = rem >> 7;
    int j2  = rem & 127;

    const float4* row0 = reinterpret_cast<const float4*>(
        x + (size_t)p * (kW * kW) + (size_t)(2 * i) * kW);
    const float4* row1 = reinterpret_cast<const float4*>(
        x + (size_t)p * (kW * kW) + (size_t)(2 * i + 1) * kW);
    float4 t = row0[j2];   // a0 b0 a1 b1
    float4 u = row1[j2];   // c0 d0 c1 d1

    float2 ll, lh, hl, hh;
    ll.x = (t.x + t.y + u.x + u.y) * 0.5f;
    ll.y = (t.z + t.w + u.z + u.w) * 0.5f;
    lh.x = (u.x + u.y - t.x - t.y) * 0.5f;
    lh.y = (u.z + u.w - t.z - t.w) * 0.5f;
    hl.x = (t.y + u.y - t.x - u.x) * 0.5f;
    hl.y = (t.w + u.w - t.z - u.z) * 0.5f;
    hh.x = (t.x + u.y - t.y - u.x) * 0.5f;
    hh.y = (t.z + u.w - t.w - u.z) * 0.5f;

    float2* outv = reinterpret_cast<float2*>(out);
    size_t ov = (size_t)p * (kOutPlane / 2) + (size_t)i * (kOutHW / 2) + j2;
    constexpr size_t Q = kOutRegion / 2;   // float2 elements per subband
    outv[ov]         = ll;
    outv[ov + Q]     = lh;
    outv[ov + 2 * Q] = hl;
    outv[ov + 3 * Q] = hh;
}

extern "C" void kernel_launch(void* const* d_in, const int* in_sizes, int n_in,
                              void* d_out, int out_size, void* d_ws, size_t ws_size,
                              hipStream_t stream) {
    const float* x = (const float*)d_in[0];
    float* out = (float*)d_out;
    // total threads = 512 planes * 256 rows * 128 col-pairs = 16,777,216
    const int total = kPlanes * kOutHW * (kOutHW / 2);
    const int block = 256;
    const int grid = total / block;   // 65536
    dwt2d_haar_kernel<<<grid, block, 0, stream>>>(x, out);
}